// Round 1
// baseline (256.219 us; speedup 1.0000x reference)
//
#include <hip/hip_runtime.h>
#include <stdint.h>

#define NEGF   (-1.0e30f)
#define LOG2E  1.4426950408889634f
#define LN2    0.6931471805599453f

// -------- log-domain (base-2) add helpers: native v_exp_f32 / v_log_f32 --------
__device__ __forceinline__ float ladd2(float a, float b) {
  float m = fmaxf(a, b);
  float n = fminf(a, b);
  return m + log2f(1.0f + exp2f(n - m));
}
__device__ __forceinline__ float ladd3(float a, float b, float c) {
  float m = fmaxf(fmaxf(a, b), c);
  float s = exp2f(a - m) + exp2f(b - m) + exp2f(c - m);
  return m + log2f(s);
}

// lane i <- lane i-1 (whole wave), lane 0 <- NEG.  DPP wave_shr:1 = 0x138.
__device__ __forceinline__ float dpp_shr1(float x) {
  int r = __builtin_amdgcn_update_dpp(__float_as_int(NEGF), __float_as_int(x),
                                      0x138, 0xf, 0xf, false);
  return __int_as_float(r);
}

// ============================================================================
// Kernel 1: per (t,b) row: lse over V, then emit 65 compacted log2-softmax
// values: [blank, lab_0 .. lab_{L-1}] with row stride 66 floats, layout (B,T,66)
// ============================================================================
__global__ __launch_bounds__(64) void k_lse_gather(
    const float* __restrict__ acts, const int* __restrict__ labels,
    float* __restrict__ lp, int T, int B, int V, int L) {
  const uint32_t r = blockIdx.x;             // r = t*B + b  (acts row index)
  const uint32_t b = r % (uint32_t)B;
  const uint32_t t = r / (uint32_t)B;
  const int lane = threadIdx.x;
  const float* __restrict__ row = acts + (size_t)r * (size_t)V;

  float mx, l2s;
  if (V == 2048) {
    // 8 x float4 per lane, row fully in registers
    const float4* row4 = (const float4*)row;
    float vals[32];
    mx = -3.0e38f;
#pragma unroll
    for (int q = 0; q < 8; ++q) {
      float4 v = row4[lane + (q << 6)];
      vals[q*4+0] = v.x; vals[q*4+1] = v.y; vals[q*4+2] = v.z; vals[q*4+3] = v.w;
      mx = fmaxf(mx, fmaxf(fmaxf(v.x, v.y), fmaxf(v.z, v.w)));
    }
#pragma unroll
    for (int off = 32; off >= 1; off >>= 1) mx = fmaxf(mx, __shfl_xor(mx, off, 64));
    float s = 0.0f;
#pragma unroll
    for (int k = 0; k < 32; ++k) s += exp2f((vals[k] - mx) * LOG2E);
#pragma unroll
    for (int off = 32; off >= 1; off >>= 1) s += __shfl_xor(s, off, 64);
    l2s = log2f(s);
  } else {
    // generic online logsumexp fallback
    float m = -3.0e38f, s = 0.0f;
    for (int i = lane; i < V; i += 64) {
      float x = row[i];
      float m2 = fmaxf(m, x);
      s = s * exp2f((m - m2) * LOG2E) + exp2f((x - m2) * LOG2E);
      m = m2;
    }
#pragma unroll
    for (int off = 32; off >= 1; off >>= 1) {
      float mo = __shfl_xor(m, off, 64), so = __shfl_xor(s, off, 64);
      float m2 = fmaxf(m, mo);
      s = s * exp2f((m - m2) * LOG2E) + so * exp2f((mo - m2) * LOG2E);
      m = m2;
    }
    mx = m;
    l2s = log2f(s);
  }

  float* __restrict__ out = lp + ((size_t)b * (size_t)T + t) * 66;
  if (lane < L) {
    int lab = labels[b * (uint32_t)L + lane];
    out[1 + lane] = (row[lab] - mx) * LOG2E - l2s;   // label log2-prob (L1 hit)
  }
  if (lane == 0) out[0] = (row[0] - mx) * LOG2E - l2s; // blank log2-prob
}

// ============================================================================
// Kernel 2: CTC forward recurrence, one wave per batch element.
// Lane i owns states s0=2i (blank pos), s1=2i+1 (label i); lane 63 also s2=128.
// ============================================================================
__global__ __launch_bounds__(64) void k_ctc_fwd(
    const float* __restrict__ lp, const int* __restrict__ labels,
    const int* __restrict__ act_lens, const int* __restrict__ label_lens,
    float* __restrict__ loss, int T, int B, int L) {
  const int b = blockIdx.x;
  const int lane = threadIdx.x;
  const int Tact = __builtin_amdgcn_readfirstlane(min(act_lens[b], T));
  const int ll   = __builtin_amdgcn_readfirstlane(min(label_lens[b], L));

  const float* __restrict__ base = lp + (size_t)b * (size_t)T * 66; // uniform
  const float* __restrict__ pl   = base + 1 + lane;                 // per-lane

  int lab_i = (lane < L) ? labels[(size_t)b * L + lane] : 0;
  int lab_p = (lane >= 1 && lane - 1 < L) ? labels[(size_t)b * L + lane - 1] : -1;
  const bool allow2 = (lane >= 1) && (lab_i != 0) && (lab_i != lab_p);

  // t = 0 init: alpha[0]=lp_blank, alpha[1]=lp_label0, rest NEG
  float lpb_i = base[0];
  float lpl_i = pl[0];
  float s0 = (lane == 0) ? lpb_i : NEGF;
  float s1 = (lane == 0) ? lpl_i : NEGF;
  float s2 = NEGF;

  float lpb0, lpb1, lpb2, lpb3, lpb4, lpb5, lpb6, lpb7;
  float lpl0, lpl1, lpl2, lpl3, lpl4, lpl5, lpl6, lpl7;

#define PRE(k, tt) { int tc = (tt); tc = (tc < Tact) ? tc : (Tact - 1);      \
                     size_t o = (size_t)tc * 66;                             \
                     lpb##k = base[o]; lpl##k = pl[o]; }
#define STEP(k) { float pa  = dpp_shr1(s1);                                  \
                  float pb_ = dpp_shr1(s0);                                  \
                  float c2  = allow2 ? pb_ : NEGF;                           \
                  float ns0 = lpb##k + ladd2(s0, pa);                        \
                  float ns1 = lpl##k + ladd3(s1, s0, c2);                    \
                  float ns2 = lpb##k + ladd2(s2, s1);                        \
                  s0 = ns0; s1 = ns1; s2 = ns2; }

  if (Tact > 1) {
    PRE(1, 1); PRE(2, 2); PRE(3, 3); PRE(4, 4); PRE(5, 5); PRE(6, 6); PRE(7, 7);
    lpb0 = lpb1; lpl0 = lpl1;  // slot 0 loaded inside the loop
    int t = 1;
    for (; t + 8 <= Tact; t += 8) {      // consume t .. t+7
      PRE(0, t + 7);  STEP(1);
      PRE(1, t + 8);  STEP(2);
      PRE(2, t + 9);  STEP(3);
      PRE(3, t + 10); STEP(4);
      PRE(4, t + 11); STEP(5);
      PRE(5, t + 12); STEP(6);
      PRE(6, t + 13); STEP(7);
      PRE(7, t + 14); STEP(0);
    }
    if (t < Tact) { STEP(1); ++t; }
    if (t < Tact) { STEP(2); ++t; }
    if (t < Tact) { STEP(3); ++t; }
    if (t < Tact) { STEP(4); ++t; }
    if (t < Tact) { STEP(5); ++t; }
    if (t < Tact) { STEP(6); ++t; }
    if (t < Tact) { STEP(7); ++t; }
  }
#undef PRE
#undef STEP

  __shared__ float A[132];
  A[2 * lane] = s0;
  A[2 * lane + 1] = s1;
  if (lane == 63) A[128] = s2;
  __syncthreads();
  if (lane == 0) {
    int sl = 2 * ll;
    float a1 = A[sl];
    float a2 = (sl >= 1) ? A[sl - 1] : NEGF;
    loss[b] = -ladd2(a1, a2) * LN2;   // back to natural log
  }
}

// ============================================================================
// Kernel 3: sum per-batch losses -> d_out[0]
// ============================================================================
__global__ __launch_bounds__(64) void k_sum(const float* __restrict__ loss,
                                            float* __restrict__ out, int B) {
  int lane = threadIdx.x;
  float s = 0.0f;
  for (int i = lane; i < B; i += 64) s += loss[i];
#pragma unroll
  for (int off = 32; off >= 1; off >>= 1) s += __shfl_xor(s, off, 64);
  if (lane == 0) out[0] = s;
}

extern "C" void kernel_launch(void* const* d_in, const int* in_sizes, int n_in,
                              void* d_out, int out_size, void* d_ws, size_t ws_size,
                              hipStream_t stream) {
  const float* acts     = (const float*)d_in[0];
  const int*   labels   = (const int*)d_in[1];
  const int*   act_lens = (const int*)d_in[2];
  const int*   label_lens = (const int*)d_in[3];

  const int B = in_sizes[2];
  const int L = in_sizes[1] / B;
  const int T = 1000;   // per reference setup_inputs (T not derivable from sizes)
  const int V = (int)((long long)in_sizes[0] / ((long long)T * (long long)B));

  float* lp    = (float*)d_ws;                       // B*T*66 floats (~8.4 MB)
  float* lossb = lp + (size_t)B * (size_t)T * 66;    // B floats

  k_lse_gather<<<dim3(T * B), dim3(64), 0, stream>>>(acts, labels, lp, T, B, V, L);
  k_ctc_fwd<<<dim3(B), dim3(64), 0, stream>>>(lp, labels, act_lens, label_lens,
                                              lossb, T, B, L);
  k_sum<<<dim3(1), dim3(64), 0, stream>>>(lossb, (float*)d_out, B);
}